// Round 1
// baseline (461.935 us; speedup 1.0000x reference)
//
#include <hip/hip_runtime.h>
#include <math.h>

#define BB 8
#define SS 2048
#define EE 1024
#define DKK 64

// ---------------------------------------------------------------------------
// Projection: P[m][d] = sum_e X[m][e] * W[d][e] + bias[d]
// M = B*S = 16384 rows. Block = 256 threads, 64 rows x 64 cols per block.
// Per-thread 4x4 register tile; E staged in 64-wide chunks.
// ---------------------------------------------------------------------------
__global__ __launch_bounds__(256) void proj_kernel(
    const float* __restrict__ X, const float* __restrict__ W,
    const float* __restrict__ bias, float* __restrict__ P) {
  __shared__ float xs[64][68];   // xs[r][e]
  __shared__ float wsh[64][68];  // wsh[e][c] (transposed W chunk)
  const int t = threadIdx.x;
  const int rg = t >> 4;  // 0..15 -> rows rg*4..+3
  const int cg = t & 15;  // 0..15 -> cols cg*4..+3
  const int row0 = blockIdx.x * 64;

  float acc[4][4];
#pragma unroll
  for (int i = 0; i < 4; ++i)
#pragma unroll
    for (int j = 0; j < 4; ++j) acc[i][j] = 0.f;

  for (int e0 = 0; e0 < EE; e0 += 64) {
    __syncthreads();
    // stage X chunk: 64 rows x 64 e
    {
      const int r = t >> 2;   // 0..63
      const int q4 = t & 3;   // 0..3
      const float* src = X + (size_t)(row0 + r) * EE + e0 + q4 * 16;
      float4 v0 = ((const float4*)src)[0];
      float4 v1 = ((const float4*)src)[1];
      float4 v2 = ((const float4*)src)[2];
      float4 v3 = ((const float4*)src)[3];
      float* dst = &xs[r][q4 * 16];
      ((float4*)dst)[0] = v0; ((float4*)dst)[1] = v1;
      ((float4*)dst)[2] = v2; ((float4*)dst)[3] = v3;
    }
    // stage W chunk transposed: wsh[e][c] = W[c][e0+e]
    {
      const int c0 = t >> 4;  // 0..15
      const int eq = t & 15;  // e-quad
#pragma unroll
      for (int pass = 0; pass < 4; ++pass) {
        const int c = c0 + pass * 16;
        float4 wv = *(const float4*)(W + (size_t)c * EE + e0 + eq * 4);
        wsh[eq * 4 + 0][c] = wv.x;
        wsh[eq * 4 + 1][c] = wv.y;
        wsh[eq * 4 + 2][c] = wv.z;
        wsh[eq * 4 + 3][c] = wv.w;
      }
    }
    __syncthreads();
    // compute: 4 rows x 4 cols, e in quads
#pragma unroll 4
    for (int e4 = 0; e4 < 64; e4 += 4) {
      float4 xv[4], wv[4];
#pragma unroll
      for (int i = 0; i < 4; ++i) xv[i] = *(const float4*)&xs[rg * 4 + i][e4];
#pragma unroll
      for (int j = 0; j < 4; ++j) wv[j] = *(const float4*)&wsh[e4 + j][cg * 4];
#pragma unroll
      for (int i = 0; i < 4; ++i) {
        acc[i][0] += xv[i].x * wv[0].x + xv[i].y * wv[1].x + xv[i].z * wv[2].x + xv[i].w * wv[3].x;
        acc[i][1] += xv[i].x * wv[0].y + xv[i].y * wv[1].y + xv[i].z * wv[2].y + xv[i].w * wv[3].y;
        acc[i][2] += xv[i].x * wv[0].z + xv[i].y * wv[1].z + xv[i].z * wv[2].z + xv[i].w * wv[3].z;
        acc[i][3] += xv[i].x * wv[0].w + xv[i].y * wv[1].w + xv[i].z * wv[2].w + xv[i].w * wv[3].w;
      }
    }
  }
  // epilogue: bias + store
  float4 bv = *(const float4*)(bias + cg * 4);
#pragma unroll
  for (int i = 0; i < 4; ++i) {
    float4 o;
    o.x = acc[i][0] + bv.x; o.y = acc[i][1] + bv.y;
    o.z = acc[i][2] + bv.z; o.w = acc[i][3] + bv.w;
    *(float4*)(P + (size_t)(row0 + rg * 4 + i) * DKK + cg * 4) = o;
  }
}

// ---------------------------------------------------------------------------
// Fused attention: block = (batch b, 32 q-rows).
// Pass A: QK^T over k-tiles of 128, mask, store raw masked scores into the
//         weights output buffer, online (m,l) per row.
// Pass B: re-read raw scores, normalize -> weights, PV GEMM.
// ---------------------------------------------------------------------------
__global__ __launch_bounds__(256) void attn_kernel(
    const float* __restrict__ Qp, const float* __restrict__ Kp,
    const float* __restrict__ Vp, const int* __restrict__ mask,
    float* __restrict__ outsc, float* __restrict__ wts) {
  __shared__ float qs[32][68];     // Q tile
  __shared__ float kv[128][68];    // K tile (pass A) / V tile (pass B)
  __shared__ float wtile[32][132]; // normalized weights tile (pass B)
  __shared__ float mrow[32], lrow[32];

  const int t = threadIdx.x;
  const int b = blockIdx.y;
  const int q0 = blockIdx.x * 32;
  const float SCALE = 0.125f;  // 1/sqrt(64)

  // stage Q tile: 32 x 64
#pragma unroll
  for (int u = 0; u < 2; ++u) {
    const int fi = t + 256 * u;          // float4 index 0..511
    const int r = fi >> 4, dq = fi & 15;
    float4 v = *(const float4*)(Qp + ((size_t)b * SS + q0 + r) * DKK + dq * 4);
    *(float4*)&qs[r][dq * 4] = v;
  }

  const int qg = t >> 5;  // 0..7  -> q rows qg*4..+3
  const int kg = t & 31;  // 0..31 -> k cols kg + 32*j

  float m_i[4], l_i[4];
#pragma unroll
  for (int i = 0; i < 4; ++i) { m_i[i] = -3.0e38f; l_i[i] = 0.f; }

  // ---------------- Pass A ----------------
  for (int kt = 0; kt < 16; ++kt) {
    __syncthreads();
    // stage K tile 128 x 64 (flat, coalesced)
#pragma unroll
    for (int u = 0; u < 8; ++u) {
      const int fi = t + 256 * u;  // float4 idx 0..2047
      const int r = fi >> 4, dq = fi & 15;
      float4 v = *(const float4*)(Kp + ((size_t)b * SS + kt * 128 + r) * DKK + dq * 4);
      *(float4*)&kv[r][dq * 4] = v;
    }
    __syncthreads();

    float sc[4][4];
#pragma unroll
    for (int i = 0; i < 4; ++i)
#pragma unroll
      for (int j = 0; j < 4; ++j) sc[i][j] = 0.f;

#pragma unroll 4
    for (int d4 = 0; d4 < 64; d4 += 4) {
      float4 qv[4], kw[4];
#pragma unroll
      for (int i = 0; i < 4; ++i) qv[i] = *(const float4*)&qs[qg * 4 + i][d4];
#pragma unroll
      for (int j = 0; j < 4; ++j) kw[j] = *(const float4*)&kv[kg + 32 * j][d4];
#pragma unroll
      for (int i = 0; i < 4; ++i)
#pragma unroll
        for (int j = 0; j < 4; ++j)
          sc[i][j] += qv[i].x * kw[j].x + qv[i].y * kw[j].y +
                      qv[i].z * kw[j].z + qv[i].w * kw[j].w;
    }

    // mask + scale + store raw + online stats
#pragma unroll
    for (int i = 0; i < 4; ++i) {
      const int qi = q0 + qg * 4 + i;
      float vals[4];
      float tmax = -3.0e38f;
#pragma unroll
      for (int j = 0; j < 4; ++j) {
        const int kk = kt * 128 + kg + 32 * j;
        const size_t idx = ((size_t)b * SS + qi) * SS + kk;
        const int mz = mask[idx];
        float s = mz ? sc[i][j] * SCALE : -1.0e9f;
        wts[idx] = s;  // raw masked score
        vals[j] = s;
        tmax = fmaxf(tmax, s);
      }
      const float nm = fmaxf(m_i[i], tmax);
      float add = 0.f;
#pragma unroll
      for (int j = 0; j < 4; ++j) add += __expf(vals[j] - nm);
      l_i[i] = l_i[i] * __expf(m_i[i] - nm) + add;
      m_i[i] = nm;
    }
  }

  // reduce (m,l) across the 32 kg-lanes (consecutive lanes within wave)
#pragma unroll
  for (int off = 16; off >= 1; off >>= 1) {
#pragma unroll
    for (int i = 0; i < 4; ++i) {
      const float om = __shfl_xor(m_i[i], off);
      const float ol = __shfl_xor(l_i[i], off);
      const float nm = fmaxf(m_i[i], om);
      l_i[i] = l_i[i] * __expf(m_i[i] - nm) + ol * __expf(om - nm);
      m_i[i] = nm;
    }
  }
  if (kg == 0) {
#pragma unroll
    for (int i = 0; i < 4; ++i) {
      mrow[qg * 4 + i] = m_i[i];
      lrow[qg * 4 + i] = l_i[i];
    }
  }
  __syncthreads();  // also drains pass-A global stores (vmcnt(0) before barrier)

  // ---------------- Pass B ----------------
  const int qh = t >> 4;    // 0..15 -> q rows qh*2..+1
  const int dq2 = t & 15;   // 0..15 -> d cols dq2*4..+3
  float pacc[2][4];
#pragma unroll
  for (int i = 0; i < 2; ++i)
#pragma unroll
    for (int c = 0; c < 4; ++c) pacc[i][c] = 0.f;

  for (int kt = 0; kt < 16; ++kt) {
    __syncthreads();
    // stage V tile 128 x 64
#pragma unroll
    for (int u = 0; u < 8; ++u) {
      const int fi = t + 256 * u;
      const int r = fi >> 4, dq = fi & 15;
      float4 v = *(const float4*)(Vp + ((size_t)b * SS + kt * 128 + r) * DKK + dq * 4);
      *(float4*)&kv[r][dq * 4] = v;
    }
    // normalize this tile's raw scores -> weights (global + LDS)
#pragma unroll
    for (int i = 0; i < 4; ++i) {
      const int qloc = qg * 4 + i;
      const float m = mrow[qloc];
      const float rl = 1.f / lrow[qloc];
#pragma unroll
      for (int j = 0; j < 4; ++j) {
        const int kk = kt * 128 + kg + 32 * j;
        const size_t idx = ((size_t)b * SS + q0 + qloc) * SS + kk;
        const float raw = wts[idx];
        const float w = __expf(raw - m) * rl;
        wts[idx] = w;
        wtile[qloc][kg + 32 * j] = w;
      }
    }
    __syncthreads();
    // PV: pacc[i2][c] += sum_k wtile[qh*2+i2][k] * V[k][dq2*4+c]
#pragma unroll 8
    for (int k4 = 0; k4 < 128; k4 += 4) {
      float4 w0 = *(const float4*)&wtile[qh * 2 + 0][k4];
      float4 w1 = *(const float4*)&wtile[qh * 2 + 1][k4];
      float4 v0 = *(const float4*)&kv[k4 + 0][dq2 * 4];
      float4 v1 = *(const float4*)&kv[k4 + 1][dq2 * 4];
      float4 v2 = *(const float4*)&kv[k4 + 2][dq2 * 4];
      float4 v3 = *(const float4*)&kv[k4 + 3][dq2 * 4];
      pacc[0][0] += w0.x * v0.x + w0.y * v1.x + w0.z * v2.x + w0.w * v3.x;
      pacc[0][1] += w0.x * v0.y + w0.y * v1.y + w0.z * v2.y + w0.w * v3.y;
      pacc[0][2] += w0.x * v0.z + w0.y * v1.z + w0.z * v2.z + w0.w * v3.z;
      pacc[0][3] += w0.x * v0.w + w0.y * v1.w + w0.z * v2.w + w0.w * v3.w;
      pacc[1][0] += w1.x * v0.x + w1.y * v1.x + w1.z * v2.x + w1.w * v3.x;
      pacc[1][1] += w1.x * v0.y + w1.y * v1.y + w1.z * v2.y + w1.w * v3.y;
      pacc[1][2] += w1.x * v0.z + w1.y * v1.z + w1.z * v2.z + w1.w * v3.z;
      pacc[1][3] += w1.x * v0.w + w1.y * v1.w + w1.z * v2.w + w1.w * v3.w;
    }
  }
  // write attention_scores
#pragma unroll
  for (int i2 = 0; i2 < 2; ++i2) {
    float4 o;
    o.x = pacc[i2][0]; o.y = pacc[i2][1]; o.z = pacc[i2][2]; o.w = pacc[i2][3];
    *(float4*)(outsc + ((size_t)b * SS + q0 + qh * 2 + i2) * DKK + dq2 * 4) = o;
  }
}

extern "C" void kernel_launch(void* const* d_in, const int* in_sizes, int n_in,
                              void* d_out, int out_size, void* d_ws, size_t ws_size,
                              hipStream_t stream) {
  (void)in_sizes; (void)n_in; (void)out_size; (void)ws_size;
  const float* k_in = (const float*)d_in[0];
  const float* q_in = (const float*)d_in[1];
  const float* v_in = (const float*)d_in[2];
  const int* mask = (const int*)d_in[3];
  const float* w_q = (const float*)d_in[4];
  const float* b_q = (const float*)d_in[5];
  const float* w_k = (const float*)d_in[6];
  const float* b_k = (const float*)d_in[7];
  const float* w_v = (const float*)d_in[8];
  const float* b_v = (const float*)d_in[9];

  float* out_scores = (float*)d_out;                          // [B,S,DK]
  float* out_weights = out_scores + (size_t)BB * SS * DKK;    // [B,S,S]

  float* Qp = (float*)d_ws;                 // [B,S,DK] fp32
  float* Kp = Qp + (size_t)BB * SS * DKK;
  float* Vp = Kp + (size_t)BB * SS * DKK;

  proj_kernel<<<256, 256, 0, stream>>>(q_in, w_q, b_q, Qp);
  proj_kernel<<<256, 256, 0, stream>>>(k_in, w_k, b_k, Kp);
  proj_kernel<<<256, 256, 0, stream>>>(v_in, w_v, b_v, Vp);
  attn_kernel<<<dim3(SS / 32, BB), 256, 0, stream>>>(Qp, Kp, Vp, mask,
                                                     out_scores, out_weights);
}

// Round 2
// 205.771 us; speedup vs baseline: 2.2449x; 2.2449x over previous
//
#include <hip/hip_runtime.h>
#include <math.h>
#include <stdint.h>

#define BB 8
#define SS 2048
#define EE 1024
#define DKK 64

typedef _Float16 half8 __attribute__((ext_vector_type(8)));
typedef float floatx4 __attribute__((ext_vector_type(4)));

__device__ __forceinline__ half8 cvt8(float4 a, float4 b) {
  half8 h;
  h[0] = (_Float16)a.x; h[1] = (_Float16)a.y; h[2] = (_Float16)a.z; h[3] = (_Float16)a.w;
  h[4] = (_Float16)b.x; h[5] = (_Float16)b.y; h[6] = (_Float16)b.z; h[7] = (_Float16)b.w;
  return h;
}

// ---------------------------------------------------------------------------
// Merged projections: blockIdx.y = 0:Q, 1:K, 2:V(transposed output).
// P[m][d] = sum_e X[m][e] * W[d][e] + bias[d].  64 rows x 64 cols per block.
// ---------------------------------------------------------------------------
__global__ __launch_bounds__(256) void proj_kernel(
    const float* __restrict__ q_in, const float* __restrict__ k_in,
    const float* __restrict__ v_in,
    const float* __restrict__ w_q, const float* __restrict__ b_q,
    const float* __restrict__ w_k, const float* __restrict__ b_k,
    const float* __restrict__ w_v, const float* __restrict__ b_v,
    float* __restrict__ Qp, float* __restrict__ Kp, float* __restrict__ VpT) {
  const int which = blockIdx.y;
  const float* X = which == 0 ? q_in : (which == 1 ? k_in : v_in);
  const float* W = which == 0 ? w_q : (which == 1 ? w_k : w_v);
  const float* bias = which == 0 ? b_q : (which == 1 ? b_k : b_v);

  __shared__ float xs[64][68];
  __shared__ float wsh[64][68];
  const int t = threadIdx.x;
  const int rg = t >> 4;
  const int cg = t & 15;
  const int row0 = blockIdx.x * 64;

  float acc[4][4];
#pragma unroll
  for (int i = 0; i < 4; ++i)
#pragma unroll
    for (int j = 0; j < 4; ++j) acc[i][j] = 0.f;

  for (int e0 = 0; e0 < EE; e0 += 64) {
    __syncthreads();
    {
      const int r = t >> 2;
      const int q4 = t & 3;
      const float* src = X + (size_t)(row0 + r) * EE + e0 + q4 * 16;
      float4 v0 = ((const float4*)src)[0];
      float4 v1 = ((const float4*)src)[1];
      float4 v2 = ((const float4*)src)[2];
      float4 v3 = ((const float4*)src)[3];
      float* dst = &xs[r][q4 * 16];
      ((float4*)dst)[0] = v0; ((float4*)dst)[1] = v1;
      ((float4*)dst)[2] = v2; ((float4*)dst)[3] = v3;
    }
    {
      const int c0 = t >> 4;
      const int eq = t & 15;
#pragma unroll
      for (int pass = 0; pass < 4; ++pass) {
        const int c = c0 + pass * 16;
        float4 wv = *(const float4*)(W + (size_t)c * EE + e0 + eq * 4);
        wsh[eq * 4 + 0][c] = wv.x;
        wsh[eq * 4 + 1][c] = wv.y;
        wsh[eq * 4 + 2][c] = wv.z;
        wsh[eq * 4 + 3][c] = wv.w;
      }
    }
    __syncthreads();
#pragma unroll 4
    for (int e4 = 0; e4 < 64; e4 += 4) {
      float4 xv[4], wv[4];
#pragma unroll
      for (int i = 0; i < 4; ++i) xv[i] = *(const float4*)&xs[rg * 4 + i][e4];
#pragma unroll
      for (int j = 0; j < 4; ++j) wv[j] = *(const float4*)&wsh[e4 + j][cg * 4];
#pragma unroll
      for (int i = 0; i < 4; ++i) {
        acc[i][0] += xv[i].x * wv[0].x + xv[i].y * wv[1].x + xv[i].z * wv[2].x + xv[i].w * wv[3].x;
        acc[i][1] += xv[i].x * wv[0].y + xv[i].y * wv[1].y + xv[i].z * wv[2].y + xv[i].w * wv[3].y;
        acc[i][2] += xv[i].x * wv[0].z + xv[i].y * wv[1].z + xv[i].z * wv[2].z + xv[i].w * wv[3].z;
        acc[i][3] += xv[i].x * wv[0].w + xv[i].y * wv[1].w + xv[i].z * wv[2].w + xv[i].w * wv[3].w;
      }
    }
  }
  float4 bv = *(const float4*)(bias + cg * 4);
  if (which < 2) {
    float* P = (which == 0) ? Qp : Kp;
#pragma unroll
    for (int i = 0; i < 4; ++i) {
      float4 o;
      o.x = acc[i][0] + bv.x; o.y = acc[i][1] + bv.y;
      o.z = acc[i][2] + bv.z; o.w = acc[i][3] + bv.w;
      *(float4*)(P + (size_t)(row0 + rg * 4 + i) * DKK + cg * 4) = o;
    }
  } else {
    // V transposed: VpT[b][d][s]
    const int bb = row0 >> 11;
    const int s0 = row0 & (SS - 1);
    const float bvv[4] = {bv.x, bv.y, bv.z, bv.w};
#pragma unroll
    for (int i = 0; i < 4; ++i) {
#pragma unroll
      for (int j = 0; j < 4; ++j) {
        VpT[((size_t)bb * DKK + cg * 4 + j) * SS + s0 + rg * 4 + i] = acc[i][j] + bvv[j];
      }
    }
  }
}

// ---------------------------------------------------------------------------
// Fused attention, fp16 MFMA.  Block = 512 thr (8 waves), 32 q-rows, batch b.
// Wave (qhalf, cq): q-rows qhalf*16..+15, k-col blocks cq*2, cq*2+1 per tile.
// Pass A: stream K-tiles (128), QK^T via MFMA, mask (bits cached in LDS),
//         online (m,l).  Pass B: recompute QK^T, normalize -> write weights
//         once, P->LDS(fp16), PV via MFMA.
// Fragment layouts (gfx950 16x16x32, m89/m92/m97-verified):
//   A: row=l&15, k=(l>>4)*8+j (contig 8) | B: col=l&15, k=(l>>4)*8+j
//   C/D: col=l&15, row=(l>>4)*4+reg
// ---------------------------------------------------------------------------
__global__ __launch_bounds__(512, 4) void attn_kernel(
    const float* __restrict__ Qp, const float* __restrict__ Kp,
    const float* __restrict__ VpT, const int* __restrict__ mask,
    float* __restrict__ outsc, float* __restrict__ wts) {
  __shared__ __align__(16) char Kraw[128 * 128];      // K tile fp16, swizzled
  __shared__ __align__(16) char Vraw[64 * 256];       // V^T tile fp16, swizzled
  __shared__ __align__(16) char Praw[2 * 16 * 272];   // P fp16 per qhalf
  __shared__ uint32_t mbits[512][5];                  // mask bits (pad->5)
  __shared__ float mlb[2][4][16][2];                  // partial (m,l)

  const int t = threadIdx.x;
  const int b = blockIdx.x & 7;              // batch -> XCD affinity
  const int q0 = (blockIdx.x >> 3) * 32;
  const int l = t & 63;
  const int g = l >> 4, li = l & 15;
  const int w = t >> 6;
  const int qhalf = w & 1, cq = w >> 1;      // cq in 0..3
  const float SCALE = 0.125f;

  // Q A-fragments (rows qhalf*16+li), held in registers for both passes.
  half8 aq[2];
  {
    const float* qptr = Qp + ((size_t)b * SS + q0 + qhalf * 16 + li) * DKK;
#pragma unroll
    for (int h = 0; h < 2; ++h) {
      float4 a = *(const float4*)(qptr + h * 32 + g * 8);
      float4 c4 = *(const float4*)(qptr + h * 32 + g * 8 + 4);
      aq[h] = cvt8(a, c4);
    }
  }

  float m_r[4], l_r[4], rl_r[4];
#pragma unroll
  for (int r = 0; r < 4; ++r) { m_r[r] = -3.0e38f; l_r[r] = 0.f; }
#pragma unroll
  for (int i = 0; i < 4; ++i) mbits[t][i] = 0;

  const size_t qrow0 = (size_t)b * SS + q0 + qhalf * 16 + g * 4;  // + r

  // ---------------- Pass A: (m,l) only ----------------
  for (int kt = 0; kt < 16; ++kt) {
    __syncthreads();
    {  // stage K tile 128x64 -> fp16, chunk-XOR swizzle
      const int kr = t >> 3, c = t & 7;
#pragma unroll
      for (int p = 0; p < 2; ++p) {
        const int kk = kr + p * 64;
        const float* src = Kp + ((size_t)b * SS + (size_t)kt * 128 + kk) * DKK + c * 8;
        float4 a = ((const float4*)src)[0];
        float4 d4 = ((const float4*)src)[1];
        *(half8*)(Kraw + kk * 128 + ((c ^ (kk & 7)) * 16)) = cvt8(a, d4);
      }
    }
    __syncthreads();
    floatx4 sc[2];
#pragma unroll
    for (int cb2 = 0; cb2 < 2; ++cb2) {
      const int krow = (cq * 2 + cb2) * 16 + li;
      floatx4 acc = {0.f, 0.f, 0.f, 0.f};
#pragma unroll
      for (int h = 0; h < 2; ++h) {
        half8 bk = *(const half8*)(Kraw + krow * 128 + (((h * 4 + g) ^ (li & 7)) * 16));
        acc = __builtin_amdgcn_mfma_f32_16x16x32_f16(aq[h], bk, acc, 0, 0, 0);
      }
      sc[cb2] = acc;
    }
    uint32_t mbt = 0;
#pragma unroll
    for (int r = 0; r < 4; ++r) {
      float v0, v1;
      {
        const int kk = kt * 128 + (cq * 2 + 0) * 16 + li;
        const int mz = mask[(qrow0 + r) * SS + kk];
        v0 = mz ? sc[0][r] * SCALE : -1.0e9f;
        mbt |= (uint32_t)(mz != 0) << (0 + r);
      }
      {
        const int kk = kt * 128 + (cq * 2 + 1) * 16 + li;
        const int mz = mask[(qrow0 + r) * SS + kk];
        v1 = mz ? sc[1][r] * SCALE : -1.0e9f;
        mbt |= (uint32_t)(mz != 0) << (4 + r);
      }
      const float tmax = fmaxf(v0, v1);
      const float nm = fmaxf(m_r[r], tmax);
      l_r[r] = l_r[r] * __expf(m_r[r] - nm) + __expf(v0 - nm) + __expf(v1 - nm);
      m_r[r] = nm;
    }
    mbits[t][kt >> 2] |= mbt << ((kt & 3) * 8);
  }

  // reduce (m,l) across the 16 lanes of each li-group
#pragma unroll
  for (int off = 1; off < 16; off <<= 1) {
#pragma unroll
    for (int r = 0; r < 4; ++r) {
      const float om = __shfl_xor(m_r[r], off);
      const float ol = __shfl_xor(l_r[r], off);
      const float nm = fmaxf(m_r[r], om);
      l_r[r] = l_r[r] * __expf(m_r[r] - nm) + ol * __expf(om - nm);
      m_r[r] = nm;
    }
  }
  if (li == 0) {
#pragma unroll
    for (int r = 0; r < 4; ++r) {
      mlb[qhalf][cq][g * 4 + r][0] = m_r[r];
      mlb[qhalf][cq][g * 4 + r][1] = l_r[r];
    }
  }
  __syncthreads();
#pragma unroll
  for (int r = 0; r < 4; ++r) {
    float mm = -3.0e38f;
#pragma unroll
    for (int p = 0; p < 4; ++p) mm = fmaxf(mm, mlb[qhalf][p][g * 4 + r][0]);
    float ll = 0.f;
#pragma unroll
    for (int p = 0; p < 4; ++p)
      ll += mlb[qhalf][p][g * 4 + r][1] * __expf(mlb[qhalf][p][g * 4 + r][0] - mm);
    m_r[r] = mm;
    rl_r[r] = 1.f / ll;
  }

  // ---------------- Pass B: weights + PV ----------------
  floatx4 pacc = {0.f, 0.f, 0.f, 0.f};
  for (int kt = 0; kt < 16; ++kt) {
    __syncthreads();
    {  // stage K tile (same as pass A)
      const int kr = t >> 3, c = t & 7;
#pragma unroll
      for (int p = 0; p < 2; ++p) {
        const int kk = kr + p * 64;
        const float* src = Kp + ((size_t)b * SS + (size_t)kt * 128 + kk) * DKK + c * 8;
        float4 a = ((const float4*)src)[0];
        float4 d4 = ((const float4*)src)[1];
        *(half8*)(Kraw + kk * 128 + ((c ^ (kk & 7)) * 16)) = cvt8(a, d4);
      }
    }
    {  // stage V^T tile 64 x 128 -> fp16, swizzled
      const int dr = t >> 4, c = t & 15;
#pragma unroll
      for (int p = 0; p < 2; ++p) {
        const int d = dr + p * 32;
        const float* src = VpT + ((size_t)b * DKK + d) * SS + (size_t)kt * 128 + c * 8;
        float4 a = ((const float4*)src)[0];
        float4 e4 = ((const float4*)src)[1];
        *(half8*)(Vraw + d * 256 + ((c ^ (d & 7)) * 16)) = cvt8(a, e4);
      }
    }
    __syncthreads();
    floatx4 sc[2];
#pragma unroll
    for (int cb2 = 0; cb2 < 2; ++cb2) {
      const int krow = (cq * 2 + cb2) * 16 + li;
      floatx4 acc = {0.f, 0.f, 0.f, 0.f};
#pragma unroll
      for (int h = 0; h < 2; ++h) {
        half8 bk = *(const half8*)(Kraw + krow * 128 + (((h * 4 + g) ^ (li & 7)) * 16));
        acc = __builtin_amdgcn_mfma_f32_16x16x32_f16(aq[h], bk, acc, 0, 0, 0);
      }
      sc[cb2] = acc;
    }
    const uint32_t mbt = mbits[t][kt >> 2] >> ((kt & 3) * 8);
#pragma unroll
    for (int r = 0; r < 4; ++r) {
      const float mm = m_r[r], rl = rl_r[r];
#pragma unroll
      for (int cb2 = 0; cb2 < 2; ++cb2) {
        const int cb = cq * 2 + cb2;
        const int kk = kt * 128 + cb * 16 + li;
        const float s = ((mbt >> (cb2 * 4 + r)) & 1u) ? sc[cb2][r] * SCALE : -1.0e9f;
        const float wv = __expf(s - mm) * rl;
        wts[(qrow0 + r) * SS + kk] = wv;
        *(_Float16*)(Praw + qhalf * 4352 + (g * 4 + r) * 272 + (cb * 16 + li) * 2) =
            (_Float16)wv;
      }
    }
    __syncthreads();
    // PV: out[16q x 16d(db=cq)] += P[16q x 128kk] * V[128kk x 16d]
#pragma unroll
    for (int kb = 0; kb < 4; ++kb) {
      const half8 ap = *(const half8*)(Praw + qhalf * 4352 + li * 272 + kb * 64 + g * 16);
      const int dd = cq * 16 + li;
      const half8 bv = *(const half8*)(Vraw + dd * 256 + (((kb * 4 + g) ^ (dd & 7)) * 16));
      pacc = __builtin_amdgcn_mfma_f32_16x16x32_f16(ap, bv, pacc, 0, 0, 0);
    }
  }
#pragma unroll
  for (int r = 0; r < 4; ++r) {
    outsc[(qrow0 + r) * DKK + cq * 16 + li] = pacc[r];
  }
}

extern "C" void kernel_launch(void* const* d_in, const int* in_sizes, int n_in,
                              void* d_out, int out_size, void* d_ws, size_t ws_size,
                              hipStream_t stream) {
  (void)in_sizes; (void)n_in; (void)out_size; (void)ws_size;
  const float* k_in = (const float*)d_in[0];
  const float* q_in = (const float*)d_in[1];
  const float* v_in = (const float*)d_in[2];
  const int* mask = (const int*)d_in[3];
  const float* w_q = (const float*)d_in[4];
  const float* b_q = (const float*)d_in[5];
  const float* w_k = (const float*)d_in[6];
  const float* b_k = (const float*)d_in[7];
  const float* w_v = (const float*)d_in[8];
  const float* b_v = (const float*)d_in[9];

  float* out_scores = (float*)d_out;                         // [B,S,DK]
  float* out_weights = out_scores + (size_t)BB * SS * DKK;   // [B,S,S]

  float* Qp = (float*)d_ws;                  // [B,S,DK]
  float* Kp = Qp + (size_t)BB * SS * DKK;    // [B,S,DK]
  float* VpT = Kp + (size_t)BB * SS * DKK;   // [B,DK,S]

  proj_kernel<<<dim3(256, 3), 256, 0, stream>>>(q_in, k_in, v_in, w_q, b_q,
                                                w_k, b_k, w_v, b_v, Qp, Kp, VpT);
  attn_kernel<<<512, 512, 0, stream>>>(Qp, Kp, VpT, mask, out_scores, out_weights);
}

// Round 3
// 150.352 us; speedup vs baseline: 3.0724x; 1.3686x over previous
//
#include <hip/hip_runtime.h>
#include <math.h>
#include <stdint.h>

#define BB 8
#define SS 2048
#define EE 1024
#define DKK 64

typedef _Float16 half8 __attribute__((ext_vector_type(8)));
typedef float floatx4 __attribute__((ext_vector_type(4)));

__device__ __forceinline__ half8 cvt8(float4 a, float4 b) {
  half8 h;
  h[0] = (_Float16)a.x; h[1] = (_Float16)a.y; h[2] = (_Float16)a.z; h[3] = (_Float16)a.w;
  h[4] = (_Float16)b.x; h[5] = (_Float16)b.y; h[6] = (_Float16)b.z; h[7] = (_Float16)b.w;
  return h;
}

// split 8 fp32 -> fp16 hi + fp16 lo (residual). hi+lo reproduces fp32 to ~2^-22.
__device__ __forceinline__ void split8(float4 a, float4 b, half8& hi, half8& lo) {
  float va[8] = {a.x, a.y, a.z, a.w, b.x, b.y, b.z, b.w};
#pragma unroll
  for (int j = 0; j < 8; ++j) {
    _Float16 h = (_Float16)va[j];
    hi[j] = h;
    lo[j] = (_Float16)(va[j] - (float)h);
  }
}

// ---------------------------------------------------------------------------
// MFMA projection via split-fp16 (3-term): P = Xh*Wh + Xh*Wl + Xl*Wh + bias.
// blockIdx.y = 0:Q, 1:K, 2:V(transposed out). Tile: 64 rows x 64 cols, BK=64.
// 256 thr / 4 waves; wave w owns rows w*16..+15, all 64 cols.
// LDS fp16 tiles XOR-swizzled in 16B chunks: addr = row*128 + ((chunk^(row&7))*16).
// ---------------------------------------------------------------------------
__global__ __launch_bounds__(256, 3) void proj_kernel(
    const float* __restrict__ q_in, const float* __restrict__ k_in,
    const float* __restrict__ v_in,
    const float* __restrict__ w_q, const float* __restrict__ b_q,
    const float* __restrict__ w_k, const float* __restrict__ b_k,
    const float* __restrict__ w_v, const float* __restrict__ b_v,
    float* __restrict__ Qp, float* __restrict__ Kp, float* __restrict__ VpT) {
  const int which = blockIdx.y;
  const float* X = which == 0 ? q_in : (which == 1 ? k_in : v_in);
  const float* W = which == 0 ? w_q : (which == 1 ? w_k : w_v);
  const float* bias = which == 0 ? b_q : (which == 1 ? b_k : b_v);

  __shared__ __align__(16) char Xh[64 * 128];
  __shared__ __align__(16) char Xl[64 * 128];
  __shared__ __align__(16) char Wh[64 * 128];
  __shared__ __align__(16) char Wl[64 * 128];

  const int t = threadIdx.x;
  const int row0 = blockIdx.x * 64;
  // staging mapping
  const int sr = t >> 2;       // 0..63: X row / W col
  const int c4 = t & 3;        // 16-element k group
  // compute mapping
  const int l = t & 63;
  const int li = l & 15, g = l >> 4;
  const int w = t >> 6;

  const float* xbase = X + (size_t)(row0 + sr) * EE + c4 * 16;
  const float* wbase = W + (size_t)sr * EE + c4 * 16;

  float4 xr[4], wr[4];
#pragma unroll
  for (int u = 0; u < 4; ++u) {
    xr[u] = ((const float4*)xbase)[u];
    wr[u] = ((const float4*)wbase)[u];
  }

  floatx4 acc[4];
#pragma unroll
  for (int c = 0; c < 4; ++c) acc[c] = (floatx4){0.f, 0.f, 0.f, 0.f};

  const int xrow_off = (w * 16 + li) * 128;
  const int swz = li & 7;

  for (int e0 = 0; e0 < EE; e0 += 64) {
    half8 xh0, xl0, xh1, xl1, wh0, wl0, wh1, wl1;
    split8(xr[0], xr[1], xh0, xl0);
    split8(xr[2], xr[3], xh1, xl1);
    split8(wr[0], wr[1], wh0, wl0);
    split8(wr[2], wr[3], wh1, wl1);
    __syncthreads();  // previous compute done reading LDS
    {
      const int p0 = ((c4 * 2 + 0) ^ (sr & 7)) * 16;
      const int p1 = ((c4 * 2 + 1) ^ (sr & 7)) * 16;
      *(half8*)(Xh + sr * 128 + p0) = xh0;
      *(half8*)(Xh + sr * 128 + p1) = xh1;
      *(half8*)(Xl + sr * 128 + p0) = xl0;
      *(half8*)(Xl + sr * 128 + p1) = xl1;
      *(half8*)(Wh + sr * 128 + p0) = wh0;
      *(half8*)(Wh + sr * 128 + p1) = wh1;
      *(half8*)(Wl + sr * 128 + p0) = wl0;
      *(half8*)(Wl + sr * 128 + p1) = wl1;
    }
    if (e0 + 64 < EE) {  // prefetch next chunk; latency hides under MFMAs
#pragma unroll
      for (int u = 0; u < 4; ++u) {
        xr[u] = ((const float4*)(xbase + e0 + 64))[u];
        wr[u] = ((const float4*)(wbase + e0 + 64))[u];
      }
    }
    __syncthreads();
    half8 axh[2], axl[2];
#pragma unroll
    for (int h = 0; h < 2; ++h) {
      const int apos = ((h * 4 + g) ^ swz) * 16;
      axh[h] = *(const half8*)(Xh + xrow_off + apos);
      axl[h] = *(const half8*)(Xl + xrow_off + apos);
    }
#pragma unroll
    for (int c = 0; c < 4; ++c) {
      const int brow_off = (c * 16 + li) * 128;
#pragma unroll
      for (int h = 0; h < 2; ++h) {
        const int bpos = ((h * 4 + g) ^ swz) * 16;
        half8 bh = *(const half8*)(Wh + brow_off + bpos);
        half8 bl = *(const half8*)(Wl + brow_off + bpos);
        acc[c] = __builtin_amdgcn_mfma_f32_16x16x32_f16(axh[h], bh, acc[c], 0, 0, 0);
        acc[c] = __builtin_amdgcn_mfma_f32_16x16x32_f16(axh[h], bl, acc[c], 0, 0, 0);
        acc[c] = __builtin_amdgcn_mfma_f32_16x16x32_f16(axl[h], bh, acc[c], 0, 0, 0);
      }
    }
  }

  float bvv[4];
#pragma unroll
  for (int c = 0; c < 4; ++c) bvv[c] = bias[c * 16 + li];

  if (which < 2) {
    float* P = (which == 0) ? Qp : Kp;
#pragma unroll
    for (int c = 0; c < 4; ++c)
#pragma unroll
      for (int r = 0; r < 4; ++r)
        P[(size_t)(row0 + w * 16 + g * 4 + r) * DKK + c * 16 + li] = acc[c][r] + bvv[c];
  } else {
    const int bb = row0 >> 11;
    const int s0 = row0 & (SS - 1);
#pragma unroll
    for (int c = 0; c < 4; ++c)
#pragma unroll
      for (int r = 0; r < 4; ++r)
        VpT[((size_t)bb * DKK + c * 16 + li) * SS + s0 + w * 16 + g * 4 + r] =
            acc[c][r] + bvv[c];
  }
}

// ---------------------------------------------------------------------------
// Fused attention, fp16 MFMA (unchanged from round 2; ~69 us, passed).
// ---------------------------------------------------------------------------
__global__ __launch_bounds__(512, 4) void attn_kernel(
    const float* __restrict__ Qp, const float* __restrict__ Kp,
    const float* __restrict__ VpT, const int* __restrict__ mask,
    float* __restrict__ outsc, float* __restrict__ wts) {
  __shared__ __align__(16) char Kraw[128 * 128];
  __shared__ __align__(16) char Vraw[64 * 256];
  __shared__ __align__(16) char Praw[2 * 16 * 272];
  __shared__ uint32_t mbits[512][5];
  __shared__ float mlb[2][4][16][2];

  const int t = threadIdx.x;
  const int b = blockIdx.x & 7;
  const int q0 = (blockIdx.x >> 3) * 32;
  const int l = t & 63;
  const int g = l >> 4, li = l & 15;
  const int w = t >> 6;
  const int qhalf = w & 1, cq = w >> 1;
  const float SCALE = 0.125f;

  half8 aq[2];
  {
    const float* qptr = Qp + ((size_t)b * SS + q0 + qhalf * 16 + li) * DKK;
#pragma unroll
    for (int h = 0; h < 2; ++h) {
      float4 a = *(const float4*)(qptr + h * 32 + g * 8);
      float4 c4 = *(const float4*)(qptr + h * 32 + g * 8 + 4);
      aq[h] = cvt8(a, c4);
    }
  }

  float m_r[4], l_r[4], rl_r[4];
#pragma unroll
  for (int r = 0; r < 4; ++r) { m_r[r] = -3.0e38f; l_r[r] = 0.f; }
#pragma unroll
  for (int i = 0; i < 4; ++i) mbits[t][i] = 0;

  const size_t qrow0 = (size_t)b * SS + q0 + qhalf * 16 + g * 4;

  // ---------------- Pass A ----------------
  for (int kt = 0; kt < 16; ++kt) {
    __syncthreads();
    {
      const int kr = t >> 3, c = t & 7;
#pragma unroll
      for (int p = 0; p < 2; ++p) {
        const int kk = kr + p * 64;
        const float* src = Kp + ((size_t)b * SS + (size_t)kt * 128 + kk) * DKK + c * 8;
        float4 a = ((const float4*)src)[0];
        float4 d4 = ((const float4*)src)[1];
        *(half8*)(Kraw + kk * 128 + ((c ^ (kk & 7)) * 16)) = cvt8(a, d4);
      }
    }
    __syncthreads();
    floatx4 sc[2];
#pragma unroll
    for (int cb2 = 0; cb2 < 2; ++cb2) {
      const int krow = (cq * 2 + cb2) * 16 + li;
      floatx4 acc = {0.f, 0.f, 0.f, 0.f};
#pragma unroll
      for (int h = 0; h < 2; ++h) {
        half8 bk = *(const half8*)(Kraw + krow * 128 + (((h * 4 + g) ^ (li & 7)) * 16));
        acc = __builtin_amdgcn_mfma_f32_16x16x32_f16(aq[h], bk, acc, 0, 0, 0);
      }
      sc[cb2] = acc;
    }
    uint32_t mbt = 0;
#pragma unroll
    for (int r = 0; r < 4; ++r) {
      float v0, v1;
      {
        const int kk = kt * 128 + (cq * 2 + 0) * 16 + li;
        const int mz = mask[(qrow0 + r) * SS + kk];
        v0 = mz ? sc[0][r] * SCALE : -1.0e9f;
        mbt |= (uint32_t)(mz != 0) << (0 + r);
      }
      {
        const int kk = kt * 128 + (cq * 2 + 1) * 16 + li;
        const int mz = mask[(qrow0 + r) * SS + kk];
        v1 = mz ? sc[1][r] * SCALE : -1.0e9f;
        mbt |= (uint32_t)(mz != 0) << (4 + r);
      }
      const float tmax = fmaxf(v0, v1);
      const float nm = fmaxf(m_r[r], tmax);
      l_r[r] = l_r[r] * __expf(m_r[r] - nm) + __expf(v0 - nm) + __expf(v1 - nm);
      m_r[r] = nm;
    }
    mbits[t][kt >> 2] |= mbt << ((kt & 3) * 8);
  }

#pragma unroll
  for (int off = 1; off < 16; off <<= 1) {
#pragma unroll
    for (int r = 0; r < 4; ++r) {
      const float om = __shfl_xor(m_r[r], off);
      const float ol = __shfl_xor(l_r[r], off);
      const float nm = fmaxf(m_r[r], om);
      l_r[r] = l_r[r] * __expf(m_r[r] - nm) + ol * __expf(om - nm);
      m_r[r] = nm;
    }
  }
  if (li == 0) {
#pragma unroll
    for (int r = 0; r < 4; ++r) {
      mlb[qhalf][cq][g * 4 + r][0] = m_r[r];
      mlb[qhalf][cq][g * 4 + r][1] = l_r[r];
    }
  }
  __syncthreads();
#pragma unroll
  for (int r = 0; r < 4; ++r) {
    float mm = -3.0e38f;
#pragma unroll
    for (int p = 0; p < 4; ++p) mm = fmaxf(mm, mlb[qhalf][p][g * 4 + r][0]);
    float ll = 0.f;
#pragma unroll
    for (int p = 0; p < 4; ++p)
      ll += mlb[qhalf][p][g * 4 + r][1] * __expf(mlb[qhalf][p][g * 4 + r][0] - mm);
    m_r[r] = mm;
    rl_r[r] = 1.f / ll;
  }

  // ---------------- Pass B ----------------
  floatx4 pacc = {0.f, 0.f, 0.f, 0.f};
  for (int kt = 0; kt < 16; ++kt) {
    __syncthreads();
    {
      const int kr = t >> 3, c = t & 7;
#pragma unroll
      for (int p = 0; p < 2; ++p) {
        const int kk = kr + p * 64;
        const float* src = Kp + ((size_t)b * SS + (size_t)kt * 128 + kk) * DKK + c * 8;
        float4 a = ((const float4*)src)[0];
        float4 d4 = ((const float4*)src)[1];
        *(half8*)(Kraw + kk * 128 + ((c ^ (kk & 7)) * 16)) = cvt8(a, d4);
      }
    }
    {
      const int dr = t >> 4, c = t & 15;
#pragma unroll
      for (int p = 0; p < 2; ++p) {
        const int d = dr + p * 32;
        const float* src = VpT + ((size_t)b * DKK + d) * SS + (size_t)kt * 128 + c * 8;
        float4 a = ((const float4*)src)[0];
        float4 e4 = ((const float4*)src)[1];
        *(half8*)(Vraw + d * 256 + ((c ^ (d & 7)) * 16)) = cvt8(a, e4);
      }
    }
    __syncthreads();
    floatx4 sc[2];
#pragma unroll
    for (int cb2 = 0; cb2 < 2; ++cb2) {
      const int krow = (cq * 2 + cb2) * 16 + li;
      floatx4 acc = {0.f, 0.f, 0.f, 0.f};
#pragma unroll
      for (int h = 0; h < 2; ++h) {
        half8 bk = *(const half8*)(Kraw + krow * 128 + (((h * 4 + g) ^ (li & 7)) * 16));
        acc = __builtin_amdgcn_mfma_f32_16x16x32_f16(aq[h], bk, acc, 0, 0, 0);
      }
      sc[cb2] = acc;
    }
    const uint32_t mbt = mbits[t][kt >> 2] >> ((kt & 3) * 8);
#pragma unroll
    for (int r = 0; r < 4; ++r) {
      const float mm = m_r[r], rl = rl_r[r];
#pragma unroll
      for (int cb2 = 0; cb2 < 2; ++cb2) {
        const int cb = cq * 2 + cb2;
        const int kk = kt * 128 + cb * 16 + li;
        const float s = ((mbt >> (cb2 * 4 + r)) & 1u) ? sc[cb2][r] * SCALE : -1.0e9f;
        const float wv = __expf(s - mm) * rl;
        wts[(qrow0 + r) * SS + kk] = wv;
        *(_Float16*)(Praw + qhalf * 4352 + (g * 4 + r) * 272 + (cb * 16 + li) * 2) =
            (_Float16)wv;
      }
    }
    __syncthreads();
#pragma unroll
    for (int kb = 0; kb < 4; ++kb) {
      const half8 ap = *(const half8*)(Praw + qhalf * 4352 + li * 272 + kb * 64 + g * 16);
      const int dd = cq * 16 + li;
      const half8 bv = *(const half8*)(Vraw + dd * 256 + (((kb * 4 + g) ^ (dd & 7)) * 16));
      pacc = __builtin_amdgcn_mfma_f32_16x16x32_f16(ap, bv, pacc, 0, 0, 0);
    }
  }
#pragma unroll
  for (int r = 0; r < 4; ++r) {
    outsc[(qrow0 + r) * DKK + cq * 16 + li] = pacc[r];
  }
}

extern "C" void kernel_launch(void* const* d_in, const int* in_sizes, int n_in,
                              void* d_out, int out_size, void* d_ws, size_t ws_size,
                              hipStream_t stream) {
  (void)in_sizes; (void)n_in; (void)out_size; (void)ws_size;
  const float* k_in = (const float*)d_in[0];
  const float* q_in = (const float*)d_in[1];
  const float* v_in = (const float*)d_in[2];
  const int* mask = (const int*)d_in[3];
  const float* w_q = (const float*)d_in[4];
  const float* b_q = (const float*)d_in[5];
  const float* w_k = (const float*)d_in[6];
  const float* b_k = (const float*)d_in[7];
  const float* w_v = (const float*)d_in[8];
  const float* b_v = (const float*)d_in[9];

  float* out_scores = (float*)d_out;                         // [B,S,DK]
  float* out_weights = out_scores + (size_t)BB * SS * DKK;   // [B,S,S]

  float* Qp = (float*)d_ws;                  // [B,S,DK]
  float* Kp = Qp + (size_t)BB * SS * DKK;    // [B,S,DK]
  float* VpT = Kp + (size_t)BB * SS * DKK;   // [B,DK,S]

  proj_kernel<<<dim3(256, 3), 256, 0, stream>>>(q_in, k_in, v_in, w_q, b_q,
                                                w_k, b_k, w_v, b_v, Qp, Kp, VpT);
  attn_kernel<<<512, 512, 0, stream>>>(Qp, Kp, VpT, mask, out_scores, out_weights);
}